// Round 1
// baseline (396.295 us; speedup 1.0000x reference)
//
#include <hip/hip_runtime.h>

typedef __bf16 bf16;
typedef __bf16 bf16x8 __attribute__((ext_vector_type(8)));
typedef float  f32x4  __attribute__((ext_vector_type(4)));

#define S 512
#define DD 768
#define LL 64
#define BB 4

__device__ __forceinline__ void async_copy16(const void* g, void* l) {
    __builtin_amdgcn_global_load_lds(
        (const __attribute__((address_space(1))) unsigned int*)g,
        (__attribute__((address_space(3))) unsigned int*)l,
        16, 0, 0);
}

__device__ __forceinline__ bf16x8 scale_cvt(float4 a, float4 b, float4 ua, float4 ub) {
    bf16x8 p;
    p[0] = (bf16)(a.x * ua.x); p[1] = (bf16)(a.y * ua.y);
    p[2] = (bf16)(a.z * ua.z); p[3] = (bf16)(a.w * ua.w);
    p[4] = (bf16)(b.x * ub.x); p[5] = (bf16)(b.y * ub.y);
    p[6] = (bf16)(b.z * ub.z); p[7] = (bf16)(b.w * ub.w);
    return p;
}

// ---------------- prepass 1: dep fp32 -> bf16 ----------------
__global__ void cvt_dep_kernel(const float* __restrict__ dep, bf16* __restrict__ out) {
    int idx = (blockIdx.x * 256 + threadIdx.x) * 8;
    float4 a = *(const float4*)(dep + idx);
    float4 c = *(const float4*)(dep + idx + 4);
    bf16x8 p;
    p[0] = (bf16)a.x; p[1] = (bf16)a.y; p[2] = (bf16)a.z; p[3] = (bf16)a.w;
    p[4] = (bf16)c.x; p[5] = (bf16)c.y; p[6] = (bf16)c.z; p[7] = (bf16)c.w;
    *(bf16x8*)(out + idx) = p;
}

// ---------------- prepass 2: t2h[b,l,i], t2d'[b,l,o] (+bias) ----------------
// grid 256: bid>>7 = sel (0:head/t2h, 1:dep/t2d+bias); then b(4) x lgroup(4) x ichunk(8)
__global__ void t2_kernel(const float* __restrict__ head, const float* __restrict__ dep,
                          const float* __restrict__ W, const float* __restrict__ bias,
                          float* __restrict__ t2h, float* __restrict__ t2d) {
    __shared__ float Wl[16][DD];
    __shared__ float red[64][4][16];
    int bid = blockIdx.x;
    int sel = bid >> 7;
    int r   = bid & 127;
    int b   = r >> 5;
    int lg  = (r >> 3) & 3;
    int ic  = r & 7;
    const float* src = sel ? dep : head;
    int t = threadIdx.x;

    for (int l16 = 0; l16 < 16; ++l16) {
        const float* wp = W + (size_t)(lg * 16 + l16) * (2 * DD) + sel * DD;
        Wl[l16][t]       = wp[t];
        Wl[l16][t + 256] = wp[t + 256];
        Wl[l16][t + 512] = wp[t + 512];
    }
    __syncthreads();

    int iq = t >> 2, dq = t & 3;
    int i  = ic * 64 + iq;
    const float* rowp = src + (size_t)(b * S + i) * DD;
    float acc[16];
#pragma unroll
    for (int l16 = 0; l16 < 16; ++l16) acc[l16] = 0.f;
    for (int it = 0; it < 48; ++it) {
        int d = dq * 4 + it * 16;
        float4 x = *(const float4*)(rowp + d);
#pragma unroll
        for (int l16 = 0; l16 < 16; ++l16) {
            float4 wv = *(const float4*)&Wl[l16][d];
            acc[l16] += x.x * wv.x + x.y * wv.y + x.z * wv.z + x.w * wv.w;
        }
    }
#pragma unroll
    for (int l16 = 0; l16 < 16; ++l16) red[iq][dq][l16] = acc[l16];
    __syncthreads();

    int iq2 = t >> 2, l4 = t & 3;
    float* dst = sel ? t2d : t2h;
#pragma unroll
    for (int j = 0; j < 4; ++j) {
        int l16 = l4 * 4 + j;
        float v = red[iq2][0][l16] + red[iq2][1][l16] + red[iq2][2][l16] + red[iq2][3][l16];
        if (sel) v += bias[lg * 16 + l16];
        dst[(size_t)(b * LL + lg * 16 + l16) * S + ic * 64 + iq2] = v;
    }
}

// ---------------- main: C[b,l] = (head[b] . U[l]) @ dep[b]^T + epilogue ----------------
__global__ __launch_bounds__(256, 2) void biaffine_main(
    const float* __restrict__ head, const bf16* __restrict__ depb,
    const float* __restrict__ U, const float* __restrict__ t2h,
    const float* __restrict__ t2d, float* __restrict__ out) {
    __shared__ __align__(16) bf16 As[128][32];
    __shared__ __align__(16) bf16 Bs[128][32];
    __shared__ __align__(16) float Ulds[DD];

    const int tid  = threadIdx.x;
    const int lane = tid & 63;
    const int w    = tid >> 6;
    const int bi0  = (blockIdx.x & 3) << 7;
    const int bo0  = (blockIdx.x >> 2) << 7;
    const int l    = blockIdx.y;
    const int b    = blockIdx.z;

    {   // stage U[l] (768 f32)
        const float* up = U + (size_t)l * DD;
        Ulds[tid]       = up[tid];
        Ulds[tid + 256] = up[tid + 256];
        Ulds[tid + 512] = up[tid + 512];
    }

    // A staging: thread handles rows r1 and r1+64, slot-chunk cp; data-chunk ca = cp^sw
    const int r1 = tid >> 2;
    const int cp = tid & 3;
    const int sw = (r1 >> 1) & 3;          // same for r1 and r1+64
    const int ca = cp ^ sw;
    const float* hp0 = head + (size_t)(b * S + bi0 + r1) * DD + ca * 8;
    const float* hp1 = hp0 + (size_t)64 * DD;
    bf16* awr0 = &As[r1][cp * 8];
    bf16* awr1 = &As[r1 + 64][cp * 8];

    // B staging via global_load_lds: 2 insts/wave, 16 rows each, swizzle in global addr
    const int rB0 = w * 32 + (lane >> 2);
    const int rB1 = rB0 + 16;
    const int cpB = lane & 3;
    const bf16* bp0 = depb + (size_t)(b * S + bo0 + rB0) * DD + (cpB ^ ((rB0 >> 1) & 3)) * 8;
    const bf16* bp1 = depb + (size_t)(b * S + bo0 + rB1) * DD + (cpB ^ ((rB1 >> 1) & 3)) * 8;
    bf16* bw0 = &Bs[w * 32][0];
    bf16* bw1 = &Bs[w * 32 + 16][0];

    // fragment pointers (constant across K loop)
    const int wr = w & 1, wc = w >> 1;
    const int mrow = lane & 15, q = lane >> 4;
    const bf16* ap[4];
    const bf16* bp[4];
#pragma unroll
    for (int mi = 0; mi < 4; ++mi) {
        int rowA = wr * 64 + mi * 16 + mrow;
        ap[mi] = &As[rowA][(q ^ ((rowA >> 1) & 3)) * 8];
        int rowB = wc * 64 + mi * 16 + mrow;
        bp[mi] = &Bs[rowB][(q ^ ((rowB >> 1) & 3)) * 8];
    }

    f32x4 acc[4][4];
#pragma unroll
    for (int mi = 0; mi < 4; ++mi)
#pragma unroll
        for (int ni = 0; ni < 4; ++ni)
            acc[mi][ni] = (f32x4){0.f, 0.f, 0.f, 0.f};

    __syncthreads();   // Ulds visible

    const float* h0 = hp0;
    const float* h1 = hp1;
    const bf16*  g0 = bp0;
    const bf16*  g1 = bp1;
    for (int kt = 0; kt < 24; ++kt) {
        float4 h0a = *(const float4*)(h0);
        float4 h0b = *(const float4*)(h0 + 4);
        float4 h1a = *(const float4*)(h1);
        float4 h1b = *(const float4*)(h1 + 4);
        async_copy16(g0, bw0);
        async_copy16(g1, bw1);
        const float* uu = &Ulds[kt * 32 + ca * 8];
        float4 ua = *(const float4*)(uu);
        float4 ub = *(const float4*)(uu + 4);
        *(bf16x8*)awr0 = scale_cvt(h0a, h0b, ua, ub);
        *(bf16x8*)awr1 = scale_cvt(h1a, h1b, ua, ub);
        h0 += 32; h1 += 32; g0 += 32; g1 += 32;
        __syncthreads();

        bf16x8 af[4], bfr[4];
#pragma unroll
        for (int mi = 0; mi < 4; ++mi) af[mi]  = *(const bf16x8*)ap[mi];
#pragma unroll
        for (int ni = 0; ni < 4; ++ni) bfr[ni] = *(const bf16x8*)bp[ni];
#pragma unroll
        for (int mi = 0; mi < 4; ++mi)
#pragma unroll
            for (int ni = 0; ni < 4; ++ni)
                acc[mi][ni] = __builtin_amdgcn_mfma_f32_16x16x32_bf16(af[mi], bfr[ni], acc[mi][ni], 0, 0, 0);
        __syncthreads();
    }

    // epilogue: + t2h[row] + t2d'[col]
    const size_t bl = (size_t)(b * LL + l);
    const float* t2hp = t2h + bl * S + bi0 + wr * 64;
    const float* t2dp = t2d + bl * S + bo0 + wc * 64;
    float* outbase = out + bl * S * S;
#pragma unroll
    for (int mi = 0; mi < 4; ++mi) {
        float4 th = *(const float4*)&t2hp[mi * 16 + q * 4];
        int row0 = bi0 + wr * 64 + mi * 16 + q * 4;
#pragma unroll
        for (int ni = 0; ni < 4; ++ni) {
            int col = bo0 + wc * 64 + ni * 16 + mrow;
            float td = t2dp[ni * 16 + mrow];
            float* op = outbase + (size_t)row0 * S + col;
            op[0 * S] = acc[mi][ni][0] + th.x + td;
            op[1 * S] = acc[mi][ni][1] + th.y + td;
            op[2 * S] = acc[mi][ni][2] + th.z + td;
            op[3 * S] = acc[mi][ni][3] + th.w + td;
        }
    }
}

extern "C" void kernel_launch(void* const* d_in, const int* in_sizes, int n_in,
                              void* d_out, int out_size, void* d_ws, size_t ws_size,
                              hipStream_t stream) {
    const float* head = (const float*)d_in[0];
    const float* dep  = (const float*)d_in[1];
    const float* U    = (const float*)d_in[2];
    const float* W    = (const float*)d_in[3];
    const float* bias = (const float*)d_in[4];
    float* out = (float*)d_out;

    char*  ws   = (char*)d_ws;
    bf16*  depb = (bf16*)ws;                               // B*S*D*2   = 3,145,728 B
    float* t2h  = (float*)(ws + 3145728);                  // B*L*S*4   =   524,288 B
    float* t2d  = (float*)(ws + 3145728 + 524288);         // B*L*S*4   =   524,288 B

    cvt_dep_kernel<<<768, 256, 0, stream>>>(dep, depb);
    t2_kernel<<<256, 256, 0, stream>>>(head, dep, W, bias, t2h, t2d);
    biaffine_main<<<dim3(16, LL, BB), 256, 0, stream>>>(head, depb, U, t2h, t2d, out);
}